// Round 16
// baseline (383.602 us; speedup 1.0000x reference)
//
#include <hip/hip_runtime.h>
#include <stdint.h>

#define S_LEN 2048
#define D_MODEL 1024
#define N_HEAD 16
#define D_HEAD 64
#define N_BATCH 2
#define M_TOK (N_BATCH * S_LEN)  // 4096

typedef unsigned short u16;
typedef unsigned int u32;
typedef unsigned long long u64;
typedef __attribute__((ext_vector_type(8))) short bf16x8;
typedef __attribute__((ext_vector_type(4))) short s16x4;
typedef __attribute__((ext_vector_type(4))) float f32x4;
typedef __attribute__((ext_vector_type(4))) unsigned short u16x4;

#define MFMA16(a, b, c) __builtin_amdgcn_mfma_f32_16x16x32_bf16((a), (b), (c), 0, 0, 0)

#if defined(__has_builtin)
#if __has_builtin(__builtin_amdgcn_mfma_f32_16x16x16bf16_1k)
#define HAVE_MFMA_16x16x16 1
#define MFMA_PV(a, b, c) __builtin_amdgcn_mfma_f32_16x16x16bf16_1k((a), (b), (c), 0, 0, 0)
#endif
#endif

#define WAITCNT(n) asm volatile("s_waitcnt vmcnt(" #n ")" ::: "memory")
#define BAR() __builtin_amdgcn_s_barrier()

__device__ __forceinline__ u16 f2bf(float f) {
  unsigned int u = __float_as_uint(f);
  u = (u + 0x7FFFu + ((u >> 16) & 1u)) >> 16;
  return (u16)u;
}

__device__ __forceinline__ void gload_lds16(const u16* g, u16* l) {
  __builtin_amdgcn_global_load_lds((const __attribute__((address_space(1))) void*)g,
                                   (__attribute__((address_space(3))) void*)l, 16, 0, 0);
}

// ---------------- fp32 -> bf16 convert, all 7 tensors in one launch ----------------
#define N4BIG (M_TOK * D_MODEL / 4)     // 1048576
#define N4W (D_MODEL * D_MODEL / 4)     // 262144
__global__ __launch_bounds__(256) void cvt7_kernel(
    const float* __restrict__ sk, const float* __restrict__ sv, const float* __restrict__ sq,
    const float* __restrict__ swq, const float* __restrict__ swk, const float* __restrict__ swv,
    const float* __restrict__ swo, u16* __restrict__ dk, u16* __restrict__ dv, u16* __restrict__ dq,
    u16* __restrict__ dwq, u16* __restrict__ dwk, u16* __restrict__ dwv, u16* __restrict__ dwo) {
  const float* s;
  u16* d;
  int n4;
  switch (blockIdx.y) {
    case 0: s = sk; d = dk; n4 = N4BIG; break;
    case 1: s = sv; d = dv; n4 = N4BIG; break;
    case 2: s = sq; d = dq; n4 = N4BIG; break;
    case 3: s = swq; d = dwq; n4 = N4W; break;
    case 4: s = swk; d = dwk; n4 = N4W; break;
    case 5: s = swv; d = dwv; n4 = N4W; break;
    default: s = swo; d = dwo; n4 = N4W; break;
  }
  int i = blockIdx.x * blockDim.x + threadIdx.x;
  int stride = gridDim.x * blockDim.x;
  for (; i < n4; i += stride) {
    float4 v = ((const float4*)s)[i];
    u16x4 o = {f2bf(v.x), f2bf(v.y), f2bf(v.z), f2bf(v.w)};
    ((u16x4*)d)[i] = o;
  }
}

// ---------------- mask bit-pack: int32[4096][2048] -> u64[4096][32] -----------------
__global__ __launch_bounds__(256) void pack_mask(const int* __restrict__ mask,
                                                 u64* __restrict__ packed) {
  int wid = (blockIdx.x * blockDim.x + threadIdx.x) >> 6;
  int lane = threadIdx.x & 63;
  int nw = (gridDim.x * blockDim.x) >> 6;
  const int NW64 = M_TOK * (S_LEN / 64);  // 131072
  for (int widx = wid; widx < NW64; widx += nw) {
    int m = mask[(size_t)widx * 64 + lane];
    u64 bits = __ballot(m != 0);
    if (lane == 0) packed[widx] = bits;
  }
}

// ---------------- GEMM body: C[M,N] = A[M,K]@Bw[N,K]^T, +bias, *scale ----------------
__device__ __forceinline__ void gemm_body(const u16* __restrict__ A, const u16* __restrict__ Bw,
                                          const float* __restrict__ bias, void* __restrict__ Cout,
                                          float scale, int outmode) {
  __shared__ u16 As[128 * 32];
  __shared__ u16 Bs[128 * 32];
  const int K = D_MODEL, N = D_MODEL;
  int tid = threadIdx.x;
  int w = tid >> 6, lane = tid & 63, lg = lane >> 4, lr = lane & 15;
  int m0 = blockIdx.x * 128, n0 = blockIdx.y * 128;
  int wr = w >> 1, wc = w & 1;
  f32x4 acc[4][4] = {};
  int r0 = tid >> 2;
  int r1 = 64 + (tid >> 2);
  int kk0 = (tid & 3) * 8;
  for (int kb = 0; kb < K; kb += 32) {
    gload_lds16(A + (size_t)(m0 + r0) * K + kb + kk0, As + w * 512);
    gload_lds16(A + (size_t)(m0 + r1) * K + kb + kk0, As + 2048 + w * 512);
    gload_lds16(Bw + (size_t)(n0 + r0) * K + kb + kk0, Bs + w * 512);
    gload_lds16(Bw + (size_t)(n0 + r1) * K + kb + kk0, Bs + 2048 + w * 512);
    __syncthreads();
    bf16x8 af[4], bfr[4];
#pragma unroll
    for (int i = 0; i < 4; i++)
      af[i] = *(const bf16x8*)(As + (wr * 64 + i * 16 + lr) * 32 + lg * 8);
#pragma unroll
    for (int i = 0; i < 4; i++)
      bfr[i] = *(const bf16x8*)(Bs + (wc * 64 + i * 16 + lr) * 32 + lg * 8);
#pragma unroll
    for (int mi = 0; mi < 4; mi++)
#pragma unroll
      for (int ni = 0; ni < 4; ni++)
        acc[mi][ni] = MFMA16(af[mi], bfr[ni], acc[mi][ni]);
    __syncthreads();
  }
#pragma unroll
  for (int mi = 0; mi < 4; mi++)
#pragma unroll
    for (int ni = 0; ni < 4; ni++) {
      int col = n0 + wc * 64 + ni * 16 + lr;
      float bv = bias[col];
      if (outmode == 2) {
        int row0 = m0 + wr * 64 + mi * 16 + lg * 4;
        int bb = row0 >> 11, ss = row0 & (S_LEN - 1);
        u16x4 pk;
#pragma unroll
        for (int r = 0; r < 4; r++) pk[r] = f2bf((acc[mi][ni][r] + bv) * scale);
        *(u16x4*)((u16*)Cout + ((size_t)((bb * N_HEAD + (col >> 6)) * D_HEAD + (col & 63)) * S_LEN + ss)) = pk;
      } else {
#pragma unroll
        for (int r = 0; r < 4; r++) {
          int row = m0 + wr * 64 + mi * 16 + lg * 4 + r;
          float v = (acc[mi][ni][r] + bv) * scale;
          if (outmode == 1)
            ((float*)Cout)[(size_t)row * N + col] = v;
          else
            ((u16*)Cout)[(size_t)row * N + col] = f2bf(v);
        }
      }
    }
}

// Q scale folds 1/sqrt(64) * log2(e) so attention uses exp2 directly.
#define QSCALE 0.18033688011112042f

__global__ __launch_bounds__(256) void proj3_kernel(
    const u16* __restrict__ kbf, const u16* __restrict__ vbf, const u16* __restrict__ qbf,
    const u16* __restrict__ wkb, const u16* __restrict__ wvb, const u16* __restrict__ wqb,
    const float* __restrict__ bk, const float* __restrict__ bv, const float* __restrict__ bq,
    u16* __restrict__ kup, u16* __restrict__ vtg, u16* __restrict__ qup) {
  int z = blockIdx.z;
  if (z == 0)
    gemm_body(kbf, wkb, bk, kup, 1.0f, 0);
  else if (z == 1)
    gemm_body(vbf, wvb, bv, vtg, 1.0f, 2);
  else
    gemm_body(qbf, wqb, bq, qup, QSCALE, 0);
}

__global__ __launch_bounds__(256) void gemm_out_kernel(const u16* __restrict__ A,
                                                       const u16* __restrict__ Bw,
                                                       const float* __restrict__ bias,
                                                       float* __restrict__ C) {
  gemm_body(A, Bw, bias, C, 1.0f, 1);
}

// ---------------- attention pass 0: partial row sums, k-split x2 (r10, proven) ------
__global__ __launch_bounds__(256, 8) void attn_p0(const u16* __restrict__ Qup,
                                                  const u16* __restrict__ Kup,
                                                  const u32* __restrict__ mpack,
                                                  float* __restrict__ lsums) {
  __shared__ u16 kbuf[2][64 * 64];
  int tid = threadIdx.x;
  int w = tid >> 6, lane = tid & 63, lg = lane >> 4, lr = lane & 15;
  int fb = blockIdx.x;
  int logical = (fb & 7) * 256 + (fb >> 3);
  int khalf = logical & 1;
  int qb = (logical >> 1) & 31;
  int h = (logical >> 6) & 15;
  int b = logical >> 10;
  int q0 = qb * 64;
  int q = q0 + w * 16 + lr;
  const float NEGV = -100000000.0f;

  bf16x8 qf0, qf1;
  {
    const u16* qrow = Qup + (size_t)(b * S_LEN + q) * D_MODEL + h * D_HEAD;
    qf0 = *(const bf16x8*)(qrow + lg * 8);
    qf1 = *(const bf16x8*)(qrow + 32 + lg * 8);
  }
  const u16* Kb = Kup + (size_t)(b * S_LEN) * D_MODEL + h * D_HEAD;
  const u32* mrow = mpack + (size_t)(b * S_LEN + q) * (S_LEN / 32) + khalf * 32;

  int srow = tid >> 3;
  int schunk = (tid & 7) ^ (srow & 7);
  const u16* KgA = Kb + (size_t)(khalf * 1024 + srow) * D_MODEL + schunk * 8;
  const int sw = lr & 7;

#define STAGE_K0(bn, ktn)                                                   \
  do {                                                                      \
    const u16* _s = KgA + (size_t)(ktn) * 64 * D_MODEL;                     \
    gload_lds16(_s, &kbuf[bn][0] + w * 512);                                \
    gload_lds16(_s + (size_t)32 * D_MODEL, &kbuf[bn][2048] + w * 512);      \
  } while (0)

  float lsA = 0.f, lsB = 0.f;
#define P0_BODY(BN, MM)                                                     \
  {                                                                         \
    const u16* kc = &kbuf[BN][0];                                           \
    _Pragma("unroll") for (int t = 0; t < 4; t++) {                         \
      const u16* kr = kc + (t * 16 + lr) * 64;                              \
      bf16x8 k0 = *(const bf16x8*)(kr + ((lg ^ sw) << 3));                  \
      bf16x8 k1 = *(const bf16x8*)(kr + (((lg + 4) ^ sw) << 3));            \
      f32x4 a = {0.f, 0.f, 0.f, 0.f};                                       \
      a = MFMA16(k0, qf0, a);                                               \
      a = MFMA16(k1, qf1, a);                                               \
      u32 wbits = (t < 2) ? (MM).x : (MM).y;                                \
      _Pragma("unroll") for (int r = 0; r < 4; r++) {                       \
        int j = (t * 16 + lg * 4 + r) & 31;                                 \
        float s = ((wbits >> j) & 1u) ? NEGV : a[r];                        \
        if (r & 1) lsB += exp2f(s); else lsA += exp2f(s);                   \
      }                                                                     \
    }                                                                       \
  }

  uint2 mA, mB;
  mA = *(const uint2*)(mrow);
  STAGE_K0(0, 0);
  for (int it = 0; it < 7; it++) {
    int kt = it * 2;
    mB = *(const uint2*)(mrow + (kt + 1) * 2);
    STAGE_K0(1, kt + 1);
    WAITCNT(3);
    BAR();
    P0_BODY(0, mA);
    BAR();
    mA = *(const uint2*)(mrow + (kt + 2) * 2);
    STAGE_K0(0, kt + 2);
    WAITCNT(3);
    BAR();
    P0_BODY(1, mB);
    BAR();
  }
  mB = *(const uint2*)(mrow + 15 * 2);
  STAGE_K0(1, 15);
  WAITCNT(3);
  BAR();
  P0_BODY(0, mA);
  BAR();
  WAITCNT(0);
  BAR();
  P0_BODY(1, mB);

  float lsum = lsA + lsB;
  lsum += __shfl_xor(lsum, 16);
  lsum += __shfl_xor(lsum, 32);
  if (lg == 0) lsums[(size_t)khalf * 65536 + (size_t)(b * N_HEAD + h) * S_LEN + q] = lsum;
#undef STAGE_K0
#undef P0_BODY
}

// ---------------- attention pass 1: 32 q/wave (frag reuse), k-split x2 --------------
// grid = 1024 flat (XCD swizzled): (b, h, qx 0..15, khalf). 256 thr = 4 waves; wave w
// owns q-rows {q0+32w+lr, +16} (two 16-q sets A/B) over k in [khalf*1024, +1024),
// 16 tiles of KVBLK=64. K tile [64k][64dh] 8KB + V^T tile [64dh][64k] 8KB, dbuf =
// 32 KB. Each K-frag / V-frag read from LDS feeds BOTH q-sets -> LDS bytes per (q,k)
// halved vs r8. launch_bounds(256,4): VGPR cap 128 (no ILP strip), 4 blocks/CU = 16
// waves in 4 independent barrier groups. ctx partials f32 -> ctx0/ctx1, reduced later.
__global__ __launch_bounds__(256, 4) void attn_p1(
    const u16* __restrict__ Qup, const u16* __restrict__ Kup, const u16* __restrict__ Vt,
    const u32* __restrict__ mpack, const float* __restrict__ lsums,
    float* __restrict__ attn_out, float* __restrict__ ctx0, float* __restrict__ ctx1) {
  __shared__ u16 kbuf[2][64 * 64];  // 16 KB
  __shared__ u16 vbuf[2][64 * 64];  // 16 KB
#if !defined(HAVE_MFMA_16x16x16)
  __shared__ u16 pbuf[4][2][16 * 64];  // fallback only
#endif
  int tid = threadIdx.x;
  int w = tid >> 6, lane = tid & 63, lg = lane >> 4, lr = lane & 15;
  int fb = blockIdx.x;
  int logical = (fb & 7) * 128 + (fb >> 3);  // 1024 % 8 == 0, bijective
  int khalf = logical & 1;
  int qx = (logical >> 1) & 15;
  int h = (logical >> 5) & 15;
  int b = logical >> 9;
  int q0 = qx * 128;
  int qA = q0 + w * 32 + lr;
  int qB = qA + 16;
  const float NEGV = -100000000.0f;

  bf16x8 qfA0, qfA1, qfB0, qfB1;
  {
    const u16* qrowA = Qup + (size_t)(b * S_LEN + qA) * D_MODEL + h * D_HEAD;
    qfA0 = *(const bf16x8*)(qrowA + lg * 8);
    qfA1 = *(const bf16x8*)(qrowA + 32 + lg * 8);
    const u16* qrowB = qrowA + (size_t)16 * D_MODEL;
    qfB0 = *(const bf16x8*)(qrowB + lg * 8);
    qfB1 = *(const bf16x8*)(qrowB + 32 + lg * 8);
  }
  const u16* Kb = Kup + (size_t)(b * S_LEN) * D_MODEL + h * D_HEAD;
  const u16* Vb = Vt + (size_t)(b * N_HEAD + h) * D_HEAD * S_LEN;
  const u32* mrowA = mpack + (size_t)(b * S_LEN + qA) * (S_LEN / 32) + khalf * 32;
  const u32* mrowB = mrowA + 16 * (S_LEN / 32);
  float* attn_bA = attn_out + ((size_t)(b * N_HEAD + h) * S_LEN + qA) * S_LEN + khalf * 1024;
  float* attn_bB = attn_bA + (size_t)16 * S_LEN;

  float il2A, il2B;
  {
    size_t idxA = (size_t)(b * N_HEAD + h) * S_LEN + qA;
    float totA = lsums[idxA] + lsums[65536 + idxA];
    il2A = totA > 0.f ? -__log2f(totA) : 0.f;
    float totB = lsums[idxA + 16] + lsums[65536 + idxA + 16];
    il2B = totB > 0.f ? -__log2f(totB) : 0.f;
  }

  // staging: 256 thr -> (row = tid>>3 in 0..31, chunk = (tid&7)^(row&7)); 2 gloads/tile
  int srow = tid >> 3;
  int schunk = (tid & 7) ^ (srow & 7);
  const u16* KgA = Kb + (size_t)(khalf * 1024 + srow) * D_MODEL + schunk * 8;
  const u16* VgA = Vb + (size_t)srow * S_LEN + khalf * 1024 + schunk * 8;
  const int sw = lr & 7;

#define SK(bn, ktn)                                                          \
  do {                                                                       \
    const u16* _s = KgA + (size_t)(ktn) * 64 * D_MODEL;                      \
    gload_lds16(_s, &kbuf[bn][0] + w * 512);                                 \
    gload_lds16(_s + (size_t)32 * D_MODEL, &kbuf[bn][2048] + w * 512);       \
  } while (0)
#define SV(bn, ktn)                                                          \
  do {                                                                       \
    const u16* _s = VgA + (size_t)(ktn) * 64;                                \
    gload_lds16(_s, &vbuf[bn][0] + w * 512);                                 \
    gload_lds16(_s + (size_t)32 * S_LEN, &vbuf[bn][2048] + w * 512);         \
  } while (0)

  f32x4 ctxA[4] = {};
  f32x4 ctxB[4] = {};

#if defined(HAVE_MFMA_16x16x16)
#define P1_BODY(BN, MMA, MMB, KT)                                            \
  {                                                                          \
    const u16* kc = &kbuf[BN][0];                                            \
    const u16* vc = &vbuf[BN][0];                                            \
    _Pragma("unroll") for (int t = 0; t < 4; t++) {                          \
      const u16* kr = kc + (t * 16 + lr) * 64;                               \
      bf16x8 k0 = *(const bf16x8*)(kr + ((lg ^ sw) << 3));                   \
      bf16x8 k1 = *(const bf16x8*)(kr + (((lg + 4) ^ sw) << 3));             \
      f32x4 aA = {0.f, 0.f, 0.f, 0.f};                                       \
      aA = MFMA16(k0, qfA0, aA);                                             \
      aA = MFMA16(k1, qfA1, aA);                                             \
      f32x4 aB = {0.f, 0.f, 0.f, 0.f};                                       \
      aB = MFMA16(k0, qfB0, aB);                                             \
      aB = MFMA16(k1, qfB1, aB);                                             \
      u32 wbA = (t < 2) ? (MMA).x : (MMA).y;                                 \
      u32 wbB = (t < 2) ? (MMB).x : (MMB).y;                                 \
      f32x4 pA, pB;                                                          \
      u16x4 pbA, pbB;                                                        \
      _Pragma("unroll") for (int r = 0; r < 4; r++) {                        \
        int j = (t * 16 + lg * 4 + r) & 31;                                  \
        float sA = ((wbA >> j) & 1u) ? NEGV : (aA[r] + il2A);                \
        float vA = exp2f(sA);                                                \
        pA[r] = vA;                                                          \
        pbA[r] = f2bf(vA);                                                   \
        float sB = ((wbB >> j) & 1u) ? NEGV : (aB[r] + il2B);                \
        float vB = exp2f(sB);                                                \
        pB[r] = vB;                                                          \
        pbB[r] = f2bf(vB);                                                   \
      }                                                                      \
      *(f32x4*)(attn_bA + (KT) * 64 + t * 16 + lg * 4) = pA;                 \
      *(f32x4*)(attn_bB + (KT) * 64 + t * 16 + lg * 4) = pB;                 \
      s16x4 apA = {(short)pbA[0], (short)pbA[1], (short)pbA[2], (short)pbA[3]}; \
      s16x4 apB = {(short)pbB[0], (short)pbB[1], (short)pbB[2], (short)pbB[3]}; \
      _Pragma("unroll") for (int d = 0; d < 4; d++) {                        \
        s16x4 vf = *(const s16x4*)(vc + (d * 16 + lr) * 64 +                 \
                                   (((t * 2 + (lg >> 1)) ^ sw) << 3) +       \
                                   ((lg & 1) << 2));                         \
        ctxA[d] = MFMA_PV(apA, vf, ctxA[d]);                                 \
        ctxB[d] = MFMA_PV(apB, vf, ctxB[d]);                                 \
      }                                                                      \
    }                                                                        \
  }
#else
#define P1_BODY(BN, MMA, MMB, KT)                                            \
  {                                                                          \
    const u16* kc = &kbuf[BN][0];                                            \
    const u16* vc = &vbuf[BN][0];                                            \
    _Pragma("unroll") for (int t = 0; t < 4; t++) {                          \
      const u16* kr = kc + (t * 16 + lr) * 64;                               \
      bf16x8 k0 = *(const bf16x8*)(kr + ((lg ^ sw) << 3));                   \
      bf16x8 k1 = *(const bf16x8*)(kr + (((lg + 4) ^ sw) << 3));             \
      f32x4 aA = {0.f, 0.f, 0.f, 0.f};                                       \
      aA = MFMA16(k0, qfA0, aA);                                             \
      aA = MFMA16(k1, qfA1, aA);                                             \
      f32x4 aB = {0.f, 0.f, 0.f, 0.f};                                       \
      aB = MFMA16(k0, qfB0, aB);                                             \
      aB = MFMA16(k1, qfB1, aB);                                             \
      u32 wbA = (t < 2) ? (MMA).x : (MMA).y;                                 \
      u32 wbB = (t < 2) ? (MMB).x : (MMB).y;                                 \
      f32x4 pA, pB;                                                          \
      u16x4 pbA, pbB;                                                        \
      _Pragma("unroll") for (int r = 0; r < 4; r++) {                        \
        int j = (t * 16 + lg * 4 + r) & 31;                                  \
        float sA = ((wbA >> j) & 1u) ? NEGV : (aA[r] + il2A);                \
        float vA = exp2f(sA);                                                \
        pA[r] = vA;                                                          \
        pbA[r] = f2bf(vA);                                                   \
        float sB = ((wbB >> j) & 1u) ? NEGV : (aB[r] + il2B);                \
        float vB = exp2f(sB);                                                \
        pB[r] = vB;                                                          \
        pbB[r] = f2bf(vB);                                                   \
      }                                                                      \
      *(f32x4*)(attn_bA + (KT) * 64 + t * 16 + lg * 4) = pA;                 \
      *(f32x4*)(attn_bB + (KT) * 64 + t * 16 + lg * 4) = pB;                 \
      *(u16x4*)(&pbuf[w][0][lr * 64 + (((t * 2 + (lg >> 1)) ^ sw) << 3) +    \
                ((lg & 1) << 2)]) = pbA;                                     \
      *(u16x4*)(&pbuf[w][1][lr * 64 + (((t * 2 + (lg >> 1)) ^ sw) << 3) +    \
                ((lg & 1) << 2)]) = pbB;                                     \
    }                                                                        \
    bf16x8 paA0 = *(const bf16x8*)(&pbuf[w][0][lr * 64 + ((lg ^ sw) << 3)]);  \
    bf16x8 paA1 = *(const bf16x8*)(&pbuf[w][0][lr * 64 + (((lg + 4) ^ sw) << 3)]); \
    bf16x8 paB0 = *(const bf16x8*)(&pbuf[w][1][lr * 64 + ((lg ^ sw) << 3)]);  \
    bf16x8 paB1 = *(const bf16x8*)(&pbuf[w][1][lr * 64 + (((lg + 4) ^ sw) << 3)]); \
    _Pragma("unroll") for (int d = 0; d < 4; d++) {                          \
      const u16* vr = vc + (d * 16 + lr) * 64;                               \
      bf16x8 v0 = *(const bf16x8*)(vr + ((lg ^ sw) << 3));                   \
      bf16x8 v1 = *(const bf16x8*)(vr + (((lg + 4) ^ sw) << 3));             \
      ctxA[d] = MFMA16(paA0, v0, ctxA[d]);                                   \
      ctxA[d] = MFMA16(paA1, v1, ctxA[d]);                                   \
      ctxB[d] = MFMA16(paB0, v0, ctxB[d]);                                   \
      ctxB[d] = MFMA16(paB1, v1, ctxB[d]);                                   \
    }                                                                        \
  }
#endif

  // Ledger: group(kt) = {maskA(1), maskB(1), SK(2), SV(2)} = 6 intrinsic-countable
  // ops. Steady WAITCNT(6) leaves only the newest group; retires everything older
  // (incl. stores, however lowered) -- never under-retires. Tail WAITCNT(0).
  uint2 mAa, mAb, mBa, mBb;
  mAa = *(const uint2*)(mrowA);
  mAb = *(const uint2*)(mrowB);
  SK(0, 0);
  SV(0, 0);
  for (int it = 0; it < 7; it++) {
    int kt = it * 2;
    mBa = *(const uint2*)(mrowA + (kt + 1) * 2);
    mBb = *(const uint2*)(mrowB + (kt + 1) * 2);
    SK(1, kt + 1);
    SV(1, kt + 1);
    WAITCNT(6);
    BAR();
    P1_BODY(0, mAa, mAb, kt);
    BAR();
    mAa = *(const uint2*)(mrowA + (kt + 2) * 2);
    mAb = *(const uint2*)(mrowB + (kt + 2) * 2);
    SK(0, kt + 2);
    SV(0, kt + 2);
    WAITCNT(6);
    BAR();
    P1_BODY(1, mBa, mBb, kt + 1);
    BAR();
  }
  // kt = 14 (stages tile 15)
  mBa = *(const uint2*)(mrowA + 15 * 2);
  mBb = *(const uint2*)(mrowB + 15 * 2);
  SK(1, 15);
  SV(1, 15);
  WAITCNT(6);
  BAR();
  P1_BODY(0, mAa, mAb, 14);
  BAR();
  // kt = 15
  WAITCNT(0);
  BAR();
  P1_BODY(1, mBa, mBb, 15);

  // ctx partials (f32): khalf 0 -> ctx0 (ws), khalf 1 -> ctx1 (out region)
  float* cdst = khalf ? ctx1 : ctx0;
#pragma unroll
  for (int d = 0; d < 4; d++)
#pragma unroll
    for (int r = 0; r < 4; r++) {
      int sqA = q0 + w * 32 + lg * 4 + r;
      cdst[(size_t)(b * S_LEN + sqA) * D_MODEL + h * D_HEAD + d * 16 + lr] = ctxA[d][r];
      cdst[(size_t)(b * S_LEN + sqA + 16) * D_MODEL + h * D_HEAD + d * 16 + lr] = ctxB[d][r];
    }
#undef SK
#undef SV
#undef P1_BODY
}

// ---------------- ctx reduce: ctxb(bf16) = ctx0 + ctx1 ------------------------------
__global__ __launch_bounds__(256) void ctx_reduce(const float* __restrict__ c0,
                                                  const float* __restrict__ c1,
                                                  u16* __restrict__ dst) {
  int i = blockIdx.x * 256 + threadIdx.x;  // over 1M float4 groups
  f32x4 a = ((const f32x4*)c0)[i];
  f32x4 bv = ((const f32x4*)c1)[i];
  u16x4 o = {f2bf(a[0] + bv[0]), f2bf(a[1] + bv[1]), f2bf(a[2] + bv[2]), f2bf(a[3] + bv[3])};
  ((u16x4*)dst)[i] = o;
}

// ---------------- workspace layout (u16 units) ----------------
// Phase 1 (cvt/proj): kbf@0, vbf@4194304, qbf@8388608, weights, qup/kup/vtg.
// Phase 2 (attn): ctx0 f32 16MB @0 (over dead kbf+vbf); mask u64 1MB @O_CTX;
//                 lsums f32 512KB @O_CTX+524288; ctx1 f32 = d_out out-region.
// Phase 3: ctxb bf16 8MB @O_CTX (overwrites mask+lsums after attn done).
#define O_KBF 0u
#define O_VBF 4194304u
#define O_QBF 8388608u
#define O_WQ 12582912u
#define O_WK 13631488u
#define O_WV 14680064u
#define O_WO 15728640u
#define O_QUP 16777216u
#define O_KUP 20971520u
#define O_VUP 25165824u
#define O_CTX 29360128u
// total = 33554432 u16 = 64 MiB

extern "C" void kernel_launch(void* const* d_in, const int* in_sizes, int n_in,
                              void* d_out, int out_size, void* d_ws, size_t ws_size,
                              hipStream_t stream) {
  const float* key = (const float*)d_in[0];
  const float* value = (const float*)d_in[1];
  const float* query = (const float*)d_in[2];
  const int* mask = (const int*)d_in[3];
  const float* Wq = (const float*)d_in[4];
  const float* bq = (const float*)d_in[5];
  const float* Wk = (const float*)d_in[6];
  const float* bk = (const float*)d_in[7];
  const float* Wv = (const float*)d_in[8];
  const float* bv = (const float*)d_in[9];
  const float* Wo = (const float*)d_in[10];
  const float* bo = (const float*)d_in[11];

  u16* ws = (u16*)d_ws;
  u16* kbf = ws + O_KBF;
  u16* vbf = ws + O_VBF;
  u16* qbf = ws + O_QBF;
  u16* wqb = ws + O_WQ;
  u16* wkb = ws + O_WK;
  u16* wvb = ws + O_WV;
  u16* wob = ws + O_WO;
  u16* qup = ws + O_QUP;
  u16* kup = ws + O_KUP;
  u16* vtg = ws + O_VUP;
  u16* ctxb = ws + O_CTX;
  u64* maskp = (u64*)(ws + O_CTX);               // 1 MB (dead until ctx_reduce)
  float* lsums = (float*)(ws + O_CTX + 524288);  // 512 KB
  float* ctx0 = (float*)(ws + O_KBF);            // 16 MB over dead kbf+vbf

  float* out = (float*)d_out;
  float* attn = out + (size_t)N_BATCH * S_LEN * D_MODEL;
  float* ctx1 = out;  // out-region as f32 scratch; overwritten by gemm_out at the end

  cvt7_kernel<<<dim3(512, 7), 256, 0, stream>>>(key, value, query, Wq, Wk, Wv, Wo, kbf, vbf, qbf,
                                                wqb, wkb, wvb, wob);
  proj3_kernel<<<dim3(32, 8, 3), 256, 0, stream>>>(kbf, vbf, qbf, wkb, wvb, wqb, bk, bv, bq, kup,
                                                   vtg, qup);
  pack_mask<<<1024, 256, 0, stream>>>(mask, maskp);
  attn_p0<<<2048, 256, 0, stream>>>(qup, kup, (const u32*)maskp, lsums);
  attn_p1<<<1024, 256, 0, stream>>>(qup, kup, vtg, (const u32*)maskp, lsums, attn, ctx0, ctx1);
  ctx_reduce<<<4096, 256, 0, stream>>>(ctx0, ctx1, ctxb);
  gemm_out_kernel<<<dim3(32, 8), 256, 0, stream>>>(ctxb, wob, bo, out);
}